// Round 1
// baseline (955.569 us; speedup 1.0000x reference)
//
#include <hip/hip_runtime.h>
#include <math.h>

#define BATCH 8
#define SEQ 4096
#define DIMSZ 384
#define HEADS 6
#define DH 64
#define MTOT (BATCH * SEQ) /* 32768 */
#define KDIM 384

__device__ __forceinline__ float elu1(float x) {
    // elu(x)+1 : x>0 -> x+1 ; else exp(x)-1+1 = exp(x)
    return x > 0.f ? x + 1.f : __expf(x);
}

// ---------------------------------------------------------------------------
// Generic 64x64-tile SGEMM, K=384 fixed, row-major A[M,384], B[384,Nr], C[M,Nr]
// EPI: 0 = elu(x)+1, 1 = plain, 2 = +bias[col]
// ---------------------------------------------------------------------------
template <int EPI>
__global__ __launch_bounds__(256) void sgemm_k384(const float* __restrict__ A,
                                                  const float* __restrict__ B,
                                                  float* __restrict__ C, int Nr,
                                                  const float* __restrict__ bias) {
    __shared__ float As[8][64];  // transposed: As[k][row]
    __shared__ float Bs[8][64];  // Bs[k][col]
    const int tid = threadIdx.x;
    const int tx = tid & 15;
    const int ty = tid >> 4;
    const int row0 = blockIdx.y * 64;
    const int col0 = blockIdx.x * 64;
    const int arow = tid >> 2;          // 0..63
    const int ak = (tid & 3) * 2;       // 0,2,4,6
    const int bk = tid >> 5;            // 0..7
    const int bcol = (tid & 31) * 2;    // 0..62
    float acc[4][4] = {};
    for (int kk = 0; kk < KDIM; kk += 8) {
        float2 av = *(const float2*)&A[(size_t)(row0 + arow) * KDIM + kk + ak];
        float2 bv = *(const float2*)&B[(size_t)(kk + bk) * Nr + col0 + bcol];
        __syncthreads();
        As[ak][arow] = av.x;
        As[ak + 1][arow] = av.y;
        Bs[bk][bcol] = bv.x;
        Bs[bk][bcol + 1] = bv.y;
        __syncthreads();
#pragma unroll
        for (int k = 0; k < 8; ++k) {
            float4 a = *(const float4*)&As[k][ty * 4];
            float4 b = *(const float4*)&Bs[k][tx * 4];
            float aa[4] = {a.x, a.y, a.z, a.w};
            float bb[4] = {b.x, b.y, b.z, b.w};
#pragma unroll
            for (int i = 0; i < 4; ++i)
#pragma unroll
                for (int j = 0; j < 4; ++j)
                    acc[i][j] = fmaf(aa[i], bb[j], acc[i][j]);
        }
    }
#pragma unroll
    for (int i = 0; i < 4; ++i) {
        float r[4];
#pragma unroll
        for (int j = 0; j < 4; ++j) {
            float v = acc[i][j];
            if (EPI == 0) v = elu1(v);
            if (EPI == 2) v = v + bias[col0 + tx * 4 + j];
            r[j] = v;
        }
        float4 st = {r[0], r[1], r[2], r[3]};
        *(float4*)&C[(size_t)(row0 + ty * 4 + i) * Nr + col0 + tx * 4] = st;
    }
}

// ---------------------------------------------------------------------------
// Fused kv-projection + linear-attention state accumulation.
// Per block: one batch b, one 64-row chunk. For each head h:
//   GEMM 64x384x128 -> k_tile (elu+1) and v_tile in LDS,
//   then kv[bh] += k_tile^T @ v_tile (rank-64 update) and ksum[bh] += col-sums,
//   via fp32 atomics. k/v never hit HBM.
// ---------------------------------------------------------------------------
__global__ __launch_bounds__(256) void kvproj_kv(const float* __restrict__ xkv,
                                                 const float* __restrict__ Wkv,
                                                 float* __restrict__ kv_g,
                                                 float* __restrict__ ksum_g) {
    __shared__ float As[8][64];
    __shared__ float Bks[8][64];
    __shared__ float Bvs[8][64];
    __shared__ float kt[64][65];
    __shared__ float vt[64][65];
    const int tid = threadIdx.x;
    const int tx = tid & 15;
    const int ty = tid >> 4;
    const int b = blockIdx.x >> 6;
    const int chunk = blockIdx.x & 63;
    const int row0 = b * SEQ + chunk * 64;
    const int arow = tid >> 2;
    const int ak = (tid & 3) * 2;
    const int bk = tid >> 5;
    const int bcol = (tid & 31) * 2;
    for (int h = 0; h < HEADS; ++h) {
        float acck[4][4] = {};
        float accv[4][4] = {};
        for (int kk = 0; kk < KDIM; kk += 8) {
            float2 av = *(const float2*)&xkv[(size_t)(row0 + arow) * KDIM + kk + ak];
            float2 bkv = *(const float2*)&Wkv[(size_t)(kk + bk) * (2 * DIMSZ) + h * 64 + bcol];
            float2 bvv =
                *(const float2*)&Wkv[(size_t)(kk + bk) * (2 * DIMSZ) + DIMSZ + h * 64 + bcol];
            __syncthreads();
            As[ak][arow] = av.x;
            As[ak + 1][arow] = av.y;
            Bks[bk][bcol] = bkv.x;
            Bks[bk][bcol + 1] = bkv.y;
            Bvs[bk][bcol] = bvv.x;
            Bvs[bk][bcol + 1] = bvv.y;
            __syncthreads();
#pragma unroll
            for (int k = 0; k < 8; ++k) {
                float4 a = *(const float4*)&As[k][ty * 4];
                float4 bkf = *(const float4*)&Bks[k][tx * 4];
                float4 bvf = *(const float4*)&Bvs[k][tx * 4];
                float aa[4] = {a.x, a.y, a.z, a.w};
                float kb[4] = {bkf.x, bkf.y, bkf.z, bkf.w};
                float vb[4] = {bvf.x, bvf.y, bvf.z, bvf.w};
#pragma unroll
                for (int i = 0; i < 4; ++i)
#pragma unroll
                    for (int j = 0; j < 4; ++j) {
                        acck[i][j] = fmaf(aa[i], kb[j], acck[i][j]);
                        accv[i][j] = fmaf(aa[i], vb[j], accv[i][j]);
                    }
            }
        }
        // stage k (elu+1) / v tiles to LDS
#pragma unroll
        for (int i = 0; i < 4; ++i)
#pragma unroll
            for (int j = 0; j < 4; ++j) {
                kt[ty * 4 + i][tx * 4 + j] = elu1(acck[i][j]);
                vt[ty * 4 + i][tx * 4 + j] = accv[i][j];
            }
        __syncthreads();
        const int bh = b * HEADS + h;
        if (tid < 64) {
            float s = 0.f;
#pragma unroll
            for (int r = 0; r < 64; ++r) s += kt[r][tid];
            atomicAdd(&ksum_g[bh * 64 + tid], s);
        }
        float kva[4][4] = {};
#pragma unroll 4
        for (int r = 0; r < 64; ++r) {
            float4 a = *(const float4*)&kt[r][ty * 4];
            float4 bb = *(const float4*)&vt[r][tx * 4];
            float aa[4] = {a.x, a.y, a.z, a.w};
            float bv[4] = {bb.x, bb.y, bb.z, bb.w};
#pragma unroll
            for (int i = 0; i < 4; ++i)
#pragma unroll
                for (int j = 0; j < 4; ++j)
                    kva[i][j] = fmaf(aa[i], bv[j], kva[i][j]);
        }
#pragma unroll
        for (int i = 0; i < 4; ++i)
#pragma unroll
            for (int j = 0; j < 4; ++j)
                atomicAdd(&kv_g[(size_t)bh * 4096 + (ty * 4 + i) * 64 + tx * 4 + j],
                          kva[i][j]);
        __syncthreads();
    }
}

// ---------------------------------------------------------------------------
// attn[n, h*64+m] = z_n * sum_d q[n,d] * kv[bh][d][m],  z_n = 1/(q.ksum + 1e-6)
// ---------------------------------------------------------------------------
__global__ __launch_bounds__(256) void attn_apply(const float* __restrict__ q,
                                                  const float* __restrict__ kv_g,
                                                  const float* __restrict__ ksum_g,
                                                  float* __restrict__ attn) {
    __shared__ float qsT[64][65];  // qsT[d][n]
    __shared__ float kvs[64][65];  // kvs[d][m]
    __shared__ float ks[64];
    __shared__ float zs[64];
    const int tid = threadIdx.x;
    const int tx = tid & 15;
    const int ty = tid >> 4;
    const int bh = blockIdx.x >> 6;  // 0..47
    const int chunk = blockIdx.x & 63;
    const int b = bh / HEADS;
    const int h = bh % HEADS;
    const int row0 = b * SEQ + chunk * 64;
    {
        const int d = tid >> 2;
        const int m0 = (tid & 3) * 16;
#pragma unroll
        for (int i = 0; i < 16; i += 4) {
            float4 v = *(const float4*)&kv_g[(size_t)bh * 4096 + d * 64 + m0 + i];
            kvs[d][m0 + i] = v.x;
            kvs[d][m0 + i + 1] = v.y;
            kvs[d][m0 + i + 2] = v.z;
            kvs[d][m0 + i + 3] = v.w;
        }
        const int n = tid >> 2;
        const int d0 = (tid & 3) * 16;
#pragma unroll
        for (int i = 0; i < 16; i += 4) {
            float4 v = *(const float4*)&q[(size_t)(row0 + n) * DIMSZ + h * 64 + d0 + i];
            qsT[d0 + i][n] = v.x;
            qsT[d0 + i + 1][n] = v.y;
            qsT[d0 + i + 2][n] = v.z;
            qsT[d0 + i + 3][n] = v.w;
        }
        if (tid < 64) ks[tid] = ksum_g[bh * 64 + tid];
    }
    __syncthreads();
    if (tid < 64) {
        float s = 0.f;
#pragma unroll
        for (int d = 0; d < 64; ++d) s += qsT[d][tid] * ks[d];
        zs[tid] = 1.f / (s + 1e-6f);
    }
    __syncthreads();
    float acc[4][4] = {};
#pragma unroll 4
    for (int d = 0; d < 64; ++d) {
        float4 a = *(const float4*)&qsT[d][ty * 4];
        float4 bb = *(const float4*)&kvs[d][tx * 4];
        float aa[4] = {a.x, a.y, a.z, a.w};
        float bv[4] = {bb.x, bb.y, bb.z, bb.w};
#pragma unroll
        for (int i = 0; i < 4; ++i)
#pragma unroll
            for (int j = 0; j < 4; ++j)
                acc[i][j] = fmaf(aa[i], bv[j], acc[i][j]);
    }
#pragma unroll
    for (int i = 0; i < 4; ++i) {
        float z = zs[ty * 4 + i];
        float4 st = {acc[i][0] * z, acc[i][1] * z, acc[i][2] * z, acc[i][3] * z};
        *(float4*)&attn[(size_t)(row0 + ty * 4 + i) * DIMSZ + h * 64 + tx * 4] = st;
    }
}

extern "C" void kernel_launch(void* const* d_in, const int* in_sizes, int n_in,
                              void* d_out, int out_size, void* d_ws, size_t ws_size,
                              hipStream_t stream) {
    const float* x_q = (const float*)d_in[0];
    const float* x_kv = (const float*)d_in[1];
    const float* Wq = (const float*)d_in[2];
    const float* Wkv = (const float*)d_in[3];
    const float* Wout = (const float*)d_in[4];
    const float* bout = (const float*)d_in[5];
    float* out = (float*)d_out;

    float* ws = (float*)d_ws;
    float* q = ws;                                  // MTOT*384 floats (50.3 MB)
    float* attn = q + (size_t)MTOT * DIMSZ;         // MTOT*384 floats (50.3 MB)
    float* kv = attn + (size_t)MTOT * DIMSZ;        // 48*64*64 floats
    float* ksum = kv + 48 * 4096;                   // 48*64 floats

    hipMemsetAsync(kv, 0, (48 * 4096 + 48 * 64) * sizeof(float), stream);

    dim3 blk(256);
    // q = elu(x_q @ Wq) + 1
    sgemm_k384<0><<<dim3(DIMSZ / 64, MTOT / 64), blk, 0, stream>>>(x_q, Wq, q, DIMSZ, nullptr);
    // kv state + ksum (fused kv-projection, no k/v materialization)
    kvproj_kv<<<dim3(BATCH * 64), blk, 0, stream>>>(x_kv, Wkv, kv, ksum);
    // attn = (q @ kv) * z
    attn_apply<<<dim3(48 * 64), blk, 0, stream>>>(q, kv, ksum, attn);
    // out = attn @ Wout + bout
    sgemm_k384<2><<<dim3(DIMSZ / 64, MTOT / 64), blk, 0, stream>>>(attn, Wout, out, DIMSZ, bout);
}

// Round 2
// 316.065 us; speedup vs baseline: 3.0233x; 3.0233x over previous
//
#include <hip/hip_runtime.h>
#include <math.h>

#define BATCH 8
#define SEQ 4096
#define DIMSZ 384
#define HEADS 6
#define DH 64
#define MTOT (BATCH * SEQ) /* 32768 */
#define KD 384

typedef short short8 __attribute__((ext_vector_type(8)));
typedef float floatx4 __attribute__((ext_vector_type(4)));
typedef unsigned short ushort_t;

__device__ __forceinline__ float elu1(float x) { return x > 0.f ? x + 1.f : __expf(x); }

__device__ __forceinline__ unsigned short f2b(float f) {
    unsigned int u = __float_as_uint(f);
    u = (u + 0x7fffu + ((u >> 16) & 1u)) >> 16;
    return (unsigned short)u;
}
__device__ __forceinline__ float b2f(unsigned short u) {
    return __uint_as_float(((unsigned int)u) << 16);
}

__device__ __forceinline__ void gl16(const void* g, void* l) {
    __builtin_amdgcn_global_load_lds((const __attribute__((address_space(1))) unsigned int*)g,
                                     (__attribute__((address_space(3))) unsigned int*)l, 16, 0, 0);
}

// ---------------------------------------------------------------------------
// fp32 -> bf16 bulk convert (8 elems/thread)
// ---------------------------------------------------------------------------
__global__ __launch_bounds__(256) void conv_bf16(const float* __restrict__ src,
                                                 unsigned short* __restrict__ dst) {
    size_t i = ((size_t)blockIdx.x * 256 + threadIdx.x) * 8;
    float4 a = *(const float4*)&src[i];
    float4 b = *(const float4*)&src[i + 4];
    short8 o;
    o[0] = (short)f2b(a.x); o[1] = (short)f2b(a.y); o[2] = (short)f2b(a.z); o[3] = (short)f2b(a.w);
    o[4] = (short)f2b(b.x); o[5] = (short)f2b(b.y); o[6] = (short)f2b(b.z); o[7] = (short)f2b(b.w);
    *(short8*)&dst[i] = o;
}

// ---------------------------------------------------------------------------
// W[384][N] fp32 -> WT[N][384] bf16 (transpose + convert)
// ---------------------------------------------------------------------------
__global__ __launch_bounds__(256) void conv_wt(const float* __restrict__ W,
                                               unsigned short* __restrict__ WT, int N) {
    __shared__ float tile[32][33];
    const int n0 = blockIdx.x * 32, k0 = blockIdx.y * 32;
    const int tx = threadIdx.x & 31, ty = threadIdx.x >> 5;  // 32 x 8
#pragma unroll
    for (int i = 0; i < 32; i += 8) tile[ty + i][tx] = W[(size_t)(k0 + ty + i) * N + n0 + tx];
    __syncthreads();
#pragma unroll
    for (int i = 0; i < 32; i += 8)
        WT[(size_t)(n0 + ty + i) * KD + k0 + tx] = f2b(tile[tx][ty + i]);
}

// ---------------------------------------------------------------------------
// MFMA GEMM: A[M][384] bf16 row-major, BT[N][384] bf16 (B transposed),
// C[M][NC]. 128x128 tile, BK=32, global_load_lds staging (m97 structure).
// EPI: 0 = elu+1 -> bf16 ; 1 = col<384 ? elu+1 : id -> bf16 ; 2 = +bias -> fp32
// ---------------------------------------------------------------------------
template <int EPI, int NC>
__global__ __launch_bounds__(256) void gemm_bt(const unsigned short* __restrict__ A,
                                               const unsigned short* __restrict__ BT,
                                               void* __restrict__ Cout,
                                               const float* __restrict__ bias) {
    __shared__ __align__(16) unsigned short As[4096];  // [128 rows][32 k]
    __shared__ __align__(16) unsigned short Bs[4096];  // [128 cols][32 k]
    const int tid = threadIdx.x;
    const int lane = tid & 63;
    const int wave = tid >> 6;
    const int row0 = blockIdx.y * 128;
    const int col0 = blockIdx.x * 128;
    const int wm = (wave & 1) * 64;
    const int wn = (wave >> 1) * 64;
    const int l15 = lane & 15;
    const int qd = lane >> 4;

    const int e0 = tid * 8;
    const int r0s = e0 >> 5, c0s = e0 & 31;
    const int e1 = (256 + tid) * 8;
    const int r1s = e1 >> 5, c1s = e1 & 31;
    const unsigned short* Ab = A + (size_t)row0 * KD;
    const unsigned short* Bb = BT + (size_t)col0 * KD;
    unsigned short* lA0 = As + wave * 512;
    unsigned short* lA1 = As + 2048 + wave * 512;
    unsigned short* lB0 = Bs + wave * 512;
    unsigned short* lB1 = Bs + 2048 + wave * 512;

    floatx4 zero = {0.f, 0.f, 0.f, 0.f};
    floatx4 acc[4][4];
#pragma unroll
    for (int i = 0; i < 4; ++i)
#pragma unroll
        for (int j = 0; j < 4; ++j) acc[i][j] = zero;

    for (int kk = 0; kk < KD; kk += 32) {
        __syncthreads();
        gl16(Ab + (size_t)r0s * KD + kk + c0s, lA0);
        gl16(Ab + (size_t)r1s * KD + kk + c1s, lA1);
        gl16(Bb + (size_t)r0s * KD + kk + c0s, lB0);
        gl16(Bb + (size_t)r1s * KD + kk + c1s, lB1);
        __syncthreads();
        short8 af[4], bfr[4];
#pragma unroll
        for (int mi = 0; mi < 4; ++mi)
            af[mi] = *(const short8*)&As[(wm + mi * 16 + l15) * 32 + qd * 8];
#pragma unroll
        for (int ni = 0; ni < 4; ++ni)
            bfr[ni] = *(const short8*)&Bs[(wn + ni * 16 + l15) * 32 + qd * 8];
#pragma unroll
        for (int mi = 0; mi < 4; ++mi)
#pragma unroll
            for (int ni = 0; ni < 4; ++ni)
                acc[mi][ni] =
                    __builtin_amdgcn_mfma_f32_16x16x32_bf16(af[mi], bfr[ni], acc[mi][ni], 0, 0, 0);
    }
#pragma unroll
    for (int mi = 0; mi < 4; ++mi) {
#pragma unroll
        for (int ni = 0; ni < 4; ++ni) {
            const int rbase = row0 + wm + mi * 16 + qd * 4;
            const int col = col0 + wn + ni * 16 + l15;
            float bsv = 0.f;
            if (EPI == 2) bsv = bias[col];
#pragma unroll
            for (int r = 0; r < 4; ++r) {
                float v = acc[mi][ni][r];
                if (EPI == 0) v = elu1(v);
                if (EPI == 1 && col < DIMSZ) v = elu1(v);
                if (EPI == 2) {
                    ((float*)Cout)[(size_t)(rbase + r) * NC + col] = v + bsv;
                } else {
                    ((unsigned short*)Cout)[(size_t)(rbase + r) * NC + col] = f2b(v);
                }
            }
        }
    }
}

// ---------------------------------------------------------------------------
// kv state: kv[bh][d][m] = sum_n k[n,d] * v[n,m];  ksum[bh][d] = sum_n k[n,d]
// kvp[M][768] bf16: k = cols [0,384), v = cols [384,768). Split-K atomics.
// ---------------------------------------------------------------------------
__global__ __launch_bounds__(256) void kv_state(const unsigned short* __restrict__ kvp,
                                                float* __restrict__ kv_g,
                                                float* __restrict__ ksum_g) {
    __shared__ __align__(16) unsigned short ksh[32 * 64];
    __shared__ __align__(16) unsigned short vsh[32 * 64];
    const int bx = blockIdx.x;
    const int bh = bx >> 4;
    const int ch = bx & 15;
    const int b = bh / HEADS, h = bh % HEADS;
    const int tid = threadIdx.x;
    const int tx = tid & 15, ty = tid >> 4;
    const size_t rbase = (size_t)b * SEQ + ch * 256;
    const int e = tid * 8, sr = e >> 6, sc = e & 63;
    float acc[4][4] = {};
    float ksp[4] = {};
    for (int scn = 0; scn < 8; ++scn) {
        __syncthreads();
        const size_t grow = (rbase + scn * 32 + sr) * (2 * DIMSZ);
        *(short8*)&ksh[e] = *(const short8*)&kvp[grow + h * 64 + sc];
        *(short8*)&vsh[e] = *(const short8*)&kvp[grow + DIMSZ + h * 64 + sc];
        __syncthreads();
#pragma unroll 8
        for (int r = 0; r < 32; ++r) {
            ushort2 ka = *(const ushort2*)&ksh[r * 64 + ty * 4];
            ushort2 kb = *(const ushort2*)&ksh[r * 64 + ty * 4 + 2];
            ushort2 va = *(const ushort2*)&vsh[r * 64 + tx * 4];
            ushort2 vb = *(const ushort2*)&vsh[r * 64 + tx * 4 + 2];
            float kk[4] = {b2f(ka.x), b2f(ka.y), b2f(kb.x), b2f(kb.y)};
            float vv[4] = {b2f(va.x), b2f(va.y), b2f(vb.x), b2f(vb.y)};
#pragma unroll
            for (int i = 0; i < 4; ++i) {
#pragma unroll
                for (int j = 0; j < 4; ++j) acc[i][j] = fmaf(kk[i], vv[j], acc[i][j]);
            }
            if (tx == 0) {
#pragma unroll
                for (int i = 0; i < 4; ++i) ksp[i] += kk[i];
            }
        }
    }
#pragma unroll
    for (int i = 0; i < 4; ++i)
#pragma unroll
        for (int j = 0; j < 4; ++j)
            atomicAdd(&kv_g[(size_t)bh * 4096 + (ty * 4 + i) * 64 + tx * 4 + j], acc[i][j]);
    if (tx == 0) {
#pragma unroll
        for (int i = 0; i < 4; ++i) atomicAdd(&ksum_g[bh * 64 + ty * 4 + i], ksp[i]);
    }
}

// ---------------------------------------------------------------------------
// z[bh][n] = 1 / (sum_d q[n,d]*ksum[bh,d] + 1e-6)
// ---------------------------------------------------------------------------
__global__ __launch_bounds__(256) void z_kernel(const unsigned short* __restrict__ q,
                                                const float* __restrict__ ksum_g,
                                                float* __restrict__ zbuf) {
    __shared__ float ks[64];
    const int bx = blockIdx.x;
    const int bh = bx >> 4;
    const int ch = bx & 15;
    const int b = bh / HEADS, h = bh % HEADS;
    const int tid = threadIdx.x;
    if (tid < 64) ks[tid] = ksum_g[bh * 64 + tid];
    __syncthreads();
    const int n = ch * 256 + tid;
    const unsigned short* qr = q + (size_t)(b * SEQ + n) * KD + h * 64;
    float s = 0.f;
#pragma unroll
    for (int i = 0; i < 64; i += 8) {
        short8 v = *(const short8*)&qr[i];
#pragma unroll
        for (int j = 0; j < 8; ++j) s += b2f((unsigned short)v[j]) * ks[i + j];
    }
    zbuf[(size_t)bh * SEQ + n] = 1.f / (s + 1e-6f);
}

// ---------------------------------------------------------------------------
// attn[n, h*64+m] = z_n * sum_d q[n,d] kv[bh][d][m]  (MFMA, in-place over q)
// ---------------------------------------------------------------------------
__global__ __launch_bounds__(256) void attn_mfma(const unsigned short* __restrict__ q,
                                                 const float* __restrict__ kv_g,
                                                 const float* __restrict__ zbuf,
                                                 unsigned short* __restrict__ attn) {
    __shared__ __align__(16) unsigned short kvbs[64 * 72];  // [m][d], pad 72
    __shared__ float zs[256];
    const int bx = blockIdx.x;
    const int bh = bx >> 4;
    const int rt = bx & 15;
    const int b = bh / HEADS, h = bh % HEADS;
    const int tid = threadIdx.x;
    const int lane = tid & 63, wave = tid >> 6;
    const int l15 = lane & 15, qd = lane >> 4;
#pragma unroll
    for (int i = 0; i < 16; ++i) {
        int e = i * 256 + tid;
        int d = e >> 6, m = e & 63;
        kvbs[m * 72 + d] = f2b(kv_g[(size_t)bh * 4096 + e]);
    }
    zs[tid] = zbuf[(size_t)bh * SEQ + rt * 256 + tid];
    __syncthreads();
    const size_t rowbase = (size_t)b * SEQ + rt * 256;
    floatx4 zero = {0.f, 0.f, 0.f, 0.f};
    floatx4 acc[4][4];
#pragma unroll
    for (int i = 0; i < 4; ++i)
#pragma unroll
        for (int j = 0; j < 4; ++j) acc[i][j] = zero;
#pragma unroll
    for (int ks = 0; ks < 2; ++ks) {
        short8 bfr[4];
#pragma unroll
        for (int ni = 0; ni < 4; ++ni)
            bfr[ni] = *(const short8*)&kvbs[(ni * 16 + l15) * 72 + ks * 32 + qd * 8];
#pragma unroll
        for (int mi = 0; mi < 4; ++mi) {
            short8 af = *(const short8*)&q[(rowbase + wave * 64 + mi * 16 + l15) * KD + h * 64 +
                                           ks * 32 + qd * 8];
#pragma unroll
            for (int ni = 0; ni < 4; ++ni)
                acc[mi][ni] =
                    __builtin_amdgcn_mfma_f32_16x16x32_bf16(af, bfr[ni], acc[mi][ni], 0, 0, 0);
        }
    }
#pragma unroll
    for (int mi = 0; mi < 4; ++mi) {
#pragma unroll
        for (int ni = 0; ni < 4; ++ni) {
            const int rl = wave * 64 + mi * 16 + qd * 4;
            const int col = h * 64 + ni * 16 + l15;
#pragma unroll
            for (int r = 0; r < 4; ++r) {
                float v = acc[mi][ni][r] * zs[rl + r];
                attn[(rowbase + rl + r) * KD + col] = f2b(v);
            }
        }
    }
}

extern "C" void kernel_launch(void* const* d_in, const int* in_sizes, int n_in,
                              void* d_out, int out_size, void* d_ws, size_t ws_size,
                              hipStream_t stream) {
    const float* x_q = (const float*)d_in[0];
    const float* x_kv = (const float*)d_in[1];
    const float* Wq = (const float*)d_in[2];
    const float* Wkv = (const float*)d_in[3];
    const float* Wout = (const float*)d_in[4];
    const float* bout = (const float*)d_in[5];
    float* out = (float*)d_out;

    char* ws = (char*)d_ws;
    // layout (bytes); kvp spans [25165824, 75497472); xq_bf and q_bf alias its
    // halves AFTER kv_state has consumed kvp (stream-ordered).
    unsigned short* xkv_bf = (unsigned short*)(ws + 0);          // 25.2 MB
    unsigned short* kvp = (unsigned short*)(ws + 25165824);      // 50.3 MB
    unsigned short* xq_bf = (unsigned short*)(ws + 25165824);    // alias
    unsigned short* q_bf = (unsigned short*)(ws + 50331648);     // alias (attn in-place)
    unsigned short* WqT = (unsigned short*)(ws + 75497472);      // 0.29 MB
    unsigned short* WkvT = (unsigned short*)(ws + 75792384);     // 0.59 MB
    unsigned short* WoutT = (unsigned short*)(ws + 76382208);    // 0.29 MB
    float* kv = (float*)(ws + 76677120);                         // 0.79 MB
    float* ksum = (float*)(ws + 77463552);                       // 12 KB
    float* zbuf = (float*)(ws + 77475840);                       // 0.79 MB

    hipMemsetAsync(kv, 0, (48 * 4096 + 48 * 64) * sizeof(float), stream);

    dim3 blk(256);
    conv_wt<<<dim3(12, 12), blk, 0, stream>>>(Wq, WqT, DIMSZ);
    conv_wt<<<dim3(24, 12), blk, 0, stream>>>(Wkv, WkvT, 2 * DIMSZ);
    conv_wt<<<dim3(12, 12), blk, 0, stream>>>(Wout, WoutT, DIMSZ);
    conv_bf16<<<dim3(6144), blk, 0, stream>>>(x_kv, xkv_bf);
    // kv-projection: kvp = [elu(x_kv@Wk)+1 | x_kv@Wv]
    gemm_bt<1, 768><<<dim3(6, 256), blk, 0, stream>>>(xkv_bf, WkvT, kvp, nullptr);
    // kv state + ksum (consumes kvp; kvp dead afterwards)
    kv_state<<<dim3(768), blk, 0, stream>>>(kvp, kv, ksum);
    // q-projection (xq_bf/q_bf overwrite dead kvp region)
    conv_bf16<<<dim3(6144), blk, 0, stream>>>(x_q, xq_bf);
    gemm_bt<0, 384><<<dim3(3, 256), blk, 0, stream>>>(xq_bf, WqT, q_bf, nullptr);
    // z
    z_kernel<<<dim3(768), blk, 0, stream>>>(q_bf, ksum, zbuf);
    // attn = (q @ kv) * z  (in-place over q)
    attn_mfma<<<dim3(768), blk, 0, stream>>>(q_bf, kv, zbuf, q_bf);
    // out = attn @ Wout + bout
    gemm_bt<2, 384><<<dim3(3, 256), blk, 0, stream>>>(q_bf, WoutT, out, bout);
}

// Round 3
// 273.260 us; speedup vs baseline: 3.4969x; 1.1566x over previous
//
#include <hip/hip_runtime.h>
#include <math.h>

#define BATCH 8
#define SEQ 4096
#define DIMSZ 384
#define HEADS 6
#define DH 64
#define MTOT (BATCH * SEQ) /* 32768 */
#define KD 384

typedef short short8 __attribute__((ext_vector_type(8)));
typedef float floatx4 __attribute__((ext_vector_type(4)));
typedef unsigned short ushort4v __attribute__((ext_vector_type(4)));

__device__ __forceinline__ float elu1(float x) { return x > 0.f ? x + 1.f : __expf(x); }

__device__ __forceinline__ unsigned short f2b(float f) {
    unsigned int u = __float_as_uint(f);
    u = (u + 0x7fffu + ((u >> 16) & 1u)) >> 16;
    return (unsigned short)u;
}
__device__ __forceinline__ float b2f(unsigned short u) {
    return __uint_as_float(((unsigned int)u) << 16);
}

__device__ __forceinline__ void gl16(const void* g, void* l) {
    __builtin_amdgcn_global_load_lds((const __attribute__((address_space(1))) unsigned int*)g,
                                     (__attribute__((address_space(3))) unsigned int*)l, 16, 0, 0);
}

// ---------------------------------------------------------------------------
// fp32 -> bf16 bulk convert (8 elems/thread)
// ---------------------------------------------------------------------------
__global__ __launch_bounds__(256) void conv_bf16(const float* __restrict__ src,
                                                 unsigned short* __restrict__ dst) {
    size_t i = ((size_t)blockIdx.x * 256 + threadIdx.x) * 8;
    float4 a = *(const float4*)&src[i];
    float4 b = *(const float4*)&src[i + 4];
    short8 o;
    o[0] = (short)f2b(a.x); o[1] = (short)f2b(a.y); o[2] = (short)f2b(a.z); o[3] = (short)f2b(a.w);
    o[4] = (short)f2b(b.x); o[5] = (short)f2b(b.y); o[6] = (short)f2b(b.z); o[7] = (short)f2b(b.w);
    *(short8*)&dst[i] = o;
}

// ---------------------------------------------------------------------------
// W[384][N] fp32 -> WT[N][384] bf16 (transpose + convert)
// ---------------------------------------------------------------------------
__global__ __launch_bounds__(256) void conv_wt(const float* __restrict__ W,
                                               unsigned short* __restrict__ WT, int N) {
    __shared__ float tile[32][33];
    const int n0 = blockIdx.x * 32, k0 = blockIdx.y * 32;
    const int tx = threadIdx.x & 31, ty = threadIdx.x >> 5;  // 32 x 8
#pragma unroll
    for (int i = 0; i < 32; i += 8) tile[ty + i][tx] = W[(size_t)(k0 + ty + i) * N + n0 + tx];
    __syncthreads();
#pragma unroll
    for (int i = 0; i < 32; i += 8)
        WT[(size_t)(n0 + ty + i) * KD + k0 + tx] = f2b(tile[tx][ty + i]);
}

// ---------------------------------------------------------------------------
// MFMA GEMM: A[M][384] bf16 row-major, BT[N][384] bf16 (B transposed),
// 128x128 tile, BK=32, global_load_lds staging (m97 structure).
// EPI: 0 = elu+1 -> bf16 row-major ; 2 = +bias -> fp32 row-major ;
//      3 = (col<384 ? elu+1 : id) -> bf16 TRANSPOSED store CT[col][MTOT]
// ---------------------------------------------------------------------------
template <int EPI, int NC>
__global__ __launch_bounds__(256) void gemm_bt(const unsigned short* __restrict__ A,
                                               const unsigned short* __restrict__ BT,
                                               void* __restrict__ Cout,
                                               const float* __restrict__ bias) {
    __shared__ __align__(16) unsigned short As[4096];  // [128 rows][32 k]
    __shared__ __align__(16) unsigned short Bs[4096];  // [128 cols][32 k]
    const int tid = threadIdx.x;
    const int lane = tid & 63;
    const int wave = tid >> 6;
    const int row0 = blockIdx.y * 128;
    const int col0 = blockIdx.x * 128;
    const int wm = (wave & 1) * 64;
    const int wn = (wave >> 1) * 64;
    const int l15 = lane & 15;
    const int qd = lane >> 4;

    const int e0 = tid * 8;
    const int r0s = e0 >> 5, c0s = e0 & 31;
    const int e1 = (256 + tid) * 8;
    const int r1s = e1 >> 5, c1s = e1 & 31;
    const unsigned short* Ab = A + (size_t)row0 * KD;
    const unsigned short* Bb = BT + (size_t)col0 * KD;
    unsigned short* lA0 = As + wave * 512;
    unsigned short* lA1 = As + 2048 + wave * 512;
    unsigned short* lB0 = Bs + wave * 512;
    unsigned short* lB1 = Bs + 2048 + wave * 512;

    floatx4 zero = {0.f, 0.f, 0.f, 0.f};
    floatx4 acc[4][4];
#pragma unroll
    for (int i = 0; i < 4; ++i)
#pragma unroll
        for (int j = 0; j < 4; ++j) acc[i][j] = zero;

    for (int kk = 0; kk < KD; kk += 32) {
        __syncthreads();
        gl16(Ab + (size_t)r0s * KD + kk + c0s, lA0);
        gl16(Ab + (size_t)r1s * KD + kk + c1s, lA1);
        gl16(Bb + (size_t)r0s * KD + kk + c0s, lB0);
        gl16(Bb + (size_t)r1s * KD + kk + c1s, lB1);
        __syncthreads();
        short8 af[4], bfr[4];
#pragma unroll
        for (int mi = 0; mi < 4; ++mi)
            af[mi] = *(const short8*)&As[(wm + mi * 16 + l15) * 32 + qd * 8];
#pragma unroll
        for (int ni = 0; ni < 4; ++ni)
            bfr[ni] = *(const short8*)&Bs[(wn + ni * 16 + l15) * 32 + qd * 8];
#pragma unroll
        for (int mi = 0; mi < 4; ++mi)
#pragma unroll
            for (int ni = 0; ni < 4; ++ni)
                acc[mi][ni] =
                    __builtin_amdgcn_mfma_f32_16x16x32_bf16(af[mi], bfr[ni], acc[mi][ni], 0, 0, 0);
    }
#pragma unroll
    for (int mi = 0; mi < 4; ++mi) {
#pragma unroll
        for (int ni = 0; ni < 4; ++ni) {
            const int rbase = row0 + wm + mi * 16 + qd * 4;
            const int col = col0 + wn + ni * 16 + l15;
            if (EPI == 3) {
                ushort4v o;
#pragma unroll
                for (int r = 0; r < 4; ++r) {
                    float v = acc[mi][ni][r];
                    if (col < DIMSZ) v = elu1(v);
                    o[r] = f2b(v);
                }
                *(ushort4v*)&((unsigned short*)Cout)[(size_t)col * MTOT + rbase] = o;
            } else if (EPI == 2) {
                float bsv = bias[col];
#pragma unroll
                for (int r = 0; r < 4; ++r)
                    ((float*)Cout)[(size_t)(rbase + r) * NC + col] = acc[mi][ni][r] + bsv;
            } else {
#pragma unroll
                for (int r = 0; r < 4; ++r)
                    ((unsigned short*)Cout)[(size_t)(rbase + r) * NC + col] =
                        f2b(elu1(acc[mi][ni][r]));
            }
        }
    }
}

// ---------------------------------------------------------------------------
// kv state via MFMA: kv[bh][d][m] = sum_n k[n,d]*v[n,m], ksum fused.
// kvpT[768][MTOT] bf16 (k rows [0,384), v rows [384,768)).
// grid = 48 bh x 16 n-chunks of 256; wave w covers n-slice of 64 (2 k-steps).
// Direct global fragment loads (contiguous along n) — no staging.
// Output: non-atomic fp32 partials pkv[block][4096], pks[block][64].
// ---------------------------------------------------------------------------
__global__ __launch_bounds__(256) void kv_state_mfma(const unsigned short* __restrict__ kvpT,
                                                     float* __restrict__ pkv,
                                                     float* __restrict__ pks) {
    __shared__ float kvLDS[4096];
    __shared__ float ksLDS[64];
    const int bx = blockIdx.x;
    const int bh = bx >> 4, ch = bx & 15;
    const int b = bh / HEADS, h = bh % HEADS;
    const int tid = threadIdx.x;
    const int lane = tid & 63, wave = tid >> 6;
    const int l15 = lane & 15, qd = lane >> 4;
    const size_t nbase = (size_t)b * SEQ + ch * 256 + wave * 64;
    const unsigned short* kbase = kvpT + (size_t)(h * 64) * MTOT + nbase;
    const unsigned short* vbase = kvpT + (size_t)(DIMSZ + h * 64) * MTOT + nbase;

    floatx4 zero = {0.f, 0.f, 0.f, 0.f};
    floatx4 acc[4][4];
#pragma unroll
    for (int i = 0; i < 4; ++i)
#pragma unroll
        for (int j = 0; j < 4; ++j) acc[i][j] = zero;
    float ksa[4] = {};

#pragma unroll
    for (int t = 0; t < 2; ++t) {
        short8 af[4], bfr[4];
#pragma unroll
        for (int mi = 0; mi < 4; ++mi)
            af[mi] = *(const short8*)&kbase[(size_t)(mi * 16 + l15) * MTOT + t * 32 + qd * 8];
#pragma unroll
        for (int ni = 0; ni < 4; ++ni)
            bfr[ni] = *(const short8*)&vbase[(size_t)(ni * 16 + l15) * MTOT + t * 32 + qd * 8];
#pragma unroll
        for (int mi = 0; mi < 4; ++mi) {
#pragma unroll
            for (int j = 0; j < 8; ++j) ksa[mi] += b2f((unsigned short)af[mi][j]);
#pragma unroll
            for (int ni = 0; ni < 4; ++ni)
                acc[mi][ni] =
                    __builtin_amdgcn_mfma_f32_16x16x32_bf16(af[mi], bfr[ni], acc[mi][ni], 0, 0, 0);
        }
    }
    // ksum: reduce across the 4 quads (same l15)
#pragma unroll
    for (int mi = 0; mi < 4; ++mi) {
        float v = ksa[mi];
        v += __shfl_xor(v, 16);
        v += __shfl_xor(v, 32);
        ksa[mi] = v;
    }
    // cross-wave accumulate in LDS (sequential phases, deterministic)
    for (int w = 0; w < 4; ++w) {
        if (wave == w) {
#pragma unroll
            for (int mi = 0; mi < 4; ++mi)
#pragma unroll
                for (int ni = 0; ni < 4; ++ni)
#pragma unroll
                    for (int r = 0; r < 4; ++r) {
                        const int idx = (mi * 16 + qd * 4 + r) * 64 + ni * 16 + l15;
                        if (w == 0) kvLDS[idx] = acc[mi][ni][r];
                        else kvLDS[idx] += acc[mi][ni][r];
                    }
            if (lane < 16) {
#pragma unroll
                for (int mi = 0; mi < 4; ++mi) {
                    if (w == 0) ksLDS[mi * 16 + lane] = ksa[mi];
                    else ksLDS[mi * 16 + lane] += ksa[mi];
                }
            }
        }
        __syncthreads();
    }
    const int base = tid * 16;
#pragma unroll
    for (int i = 0; i < 16; i += 4)
        *(float4*)&pkv[(size_t)bx * 4096 + base + i] = *(float4*)&kvLDS[base + i];
    if (tid < 64) pks[bx * 64 + tid] = ksLDS[tid];
}

// ---------------------------------------------------------------------------
// reduce 16 partials per bh -> kv_g fp32, ksum_g fp32
// ---------------------------------------------------------------------------
__global__ __launch_bounds__(256) void kv_reduce(const float* __restrict__ pkv,
                                                 const float* __restrict__ pks,
                                                 float* __restrict__ kv_g,
                                                 float* __restrict__ ksum_g) {
    const int bh = blockIdx.x;
    const int tid = threadIdx.x;
    for (int i0 = tid * 4; i0 < 4096; i0 += 1024) {
        float4 s = {0.f, 0.f, 0.f, 0.f};
#pragma unroll
        for (int c = 0; c < 16; ++c) {
            float4 p = *(const float4*)&pkv[(size_t)(bh * 16 + c) * 4096 + i0];
            s.x += p.x; s.y += p.y; s.z += p.z; s.w += p.w;
        }
        *(float4*)&kv_g[(size_t)bh * 4096 + i0] = s;
    }
    if (tid < 64) {
        float s = 0.f;
#pragma unroll
        for (int c = 0; c < 16; ++c) s += pks[(bh * 16 + c) * 64 + tid];
        ksum_g[bh * 64 + tid] = s;
    }
}

// ---------------------------------------------------------------------------
// attn[n, h*64+m] = z_n * sum_d q[n,d] kv[bh][d][m]  (MFMA, z fused, in-place)
// ---------------------------------------------------------------------------
__global__ __launch_bounds__(256) void attn_mfma(const unsigned short* __restrict__ q,
                                                 const float* __restrict__ kv_g,
                                                 const float* __restrict__ ksum_g,
                                                 unsigned short* __restrict__ attn) {
    __shared__ __align__(16) unsigned short kvbs[64 * 72];  // [m][d], pad 72
    __shared__ float ksh[64];
    __shared__ float zsh[256];
    const int bx = blockIdx.x;
    const int bh = bx >> 4;
    const int rt = bx & 15;
    const int b = bh / HEADS, h = bh % HEADS;
    const int tid = threadIdx.x;
    const int lane = tid & 63, wave = tid >> 6;
    const int l15 = lane & 15, qd = lane >> 4;
#pragma unroll
    for (int i = 0; i < 16; ++i) {
        int e = i * 256 + tid;
        int d = e >> 6, m = e & 63;
        kvbs[m * 72 + d] = f2b(kv_g[(size_t)bh * 4096 + e]);
    }
    if (tid < 64) ksh[tid] = ksum_g[bh * 64 + tid];
    __syncthreads();
    const size_t rowbase = (size_t)b * SEQ + rt * 256;
    floatx4 zero = {0.f, 0.f, 0.f, 0.f};
    floatx4 acc[4][4];
#pragma unroll
    for (int i = 0; i < 4; ++i)
#pragma unroll
        for (int j = 0; j < 4; ++j) acc[i][j] = zero;
    float zp[4] = {};
#pragma unroll
    for (int ks = 0; ks < 2; ++ks) {
        short8 bfr[4];
#pragma unroll
        for (int ni = 0; ni < 4; ++ni)
            bfr[ni] = *(const short8*)&kvbs[(ni * 16 + l15) * 72 + ks * 32 + qd * 8];
#pragma unroll
        for (int mi = 0; mi < 4; ++mi) {
            short8 af = *(const short8*)&q[(rowbase + wave * 64 + mi * 16 + l15) * KD + h * 64 +
                                           ks * 32 + qd * 8];
#pragma unroll
            for (int j = 0; j < 8; ++j)
                zp[mi] += b2f((unsigned short)af[j]) * ksh[ks * 32 + qd * 8 + j];
#pragma unroll
            for (int ni = 0; ni < 4; ++ni)
                acc[mi][ni] =
                    __builtin_amdgcn_mfma_f32_16x16x32_bf16(af, bfr[ni], acc[mi][ni], 0, 0, 0);
        }
    }
    // z = 1/(q . ksum + 1e-6): reduce across quads, broadcast via LDS
#pragma unroll
    for (int mi = 0; mi < 4; ++mi) {
        float v = zp[mi];
        v += __shfl_xor(v, 16);
        v += __shfl_xor(v, 32);
        if (lane < 16) zsh[wave * 64 + mi * 16 + lane] = 1.f / (v + 1e-6f);
    }
    __syncthreads();
#pragma unroll
    for (int mi = 0; mi < 4; ++mi) {
#pragma unroll
        for (int ni = 0; ni < 4; ++ni) {
            const int rl = wave * 64 + mi * 16 + qd * 4;
            const int col = h * 64 + ni * 16 + l15;
#pragma unroll
            for (int r = 0; r < 4; ++r) {
                float v = acc[mi][ni][r] * zsh[rl + r];
                attn[(rowbase + rl + r) * KD + col] = f2b(v);
            }
        }
    }
}

extern "C" void kernel_launch(void* const* d_in, const int* in_sizes, int n_in,
                              void* d_out, int out_size, void* d_ws, size_t ws_size,
                              hipStream_t stream) {
    const float* x_q = (const float*)d_in[0];
    const float* x_kv = (const float*)d_in[1];
    const float* Wq = (const float*)d_in[2];
    const float* Wkv = (const float*)d_in[3];
    const float* Wout = (const float*)d_in[4];
    const float* bout = (const float*)d_in[5];
    float* out = (float*)d_out;

    char* ws = (char*)d_ws;
    // kvpT spans [25165824, 75497472); xq_bf/q_bf alias it AFTER kv_state_mfma
    // has consumed kvpT (stream-ordered).
    unsigned short* xkv_bf = (unsigned short*)(ws + 0);          // 25.2 MB
    unsigned short* kvpT = (unsigned short*)(ws + 25165824);     // 50.3 MB [768][32768]
    unsigned short* xq_bf = (unsigned short*)(ws + 25165824);    // alias
    unsigned short* q_bf = (unsigned short*)(ws + 50331648);     // alias (attn in-place)
    unsigned short* WqT = (unsigned short*)(ws + 75497472);      // 0.29 MB
    unsigned short* WkvT = (unsigned short*)(ws + 75792384);     // 0.59 MB
    unsigned short* WoutT = (unsigned short*)(ws + 76382208);    // 0.29 MB
    float* kv = (float*)(ws + 76677120);                         // 0.79 MB
    float* ksum = (float*)(ws + 77463552);                       // 12 KB
    float* pkv = (float*)(ws + 77475840);                        // 12.6 MB
    float* pks = (float*)(ws + 90058752);                        // 0.19 MB

    dim3 blk(256);
    conv_wt<<<dim3(12, 12), blk, 0, stream>>>(Wq, WqT, DIMSZ);
    conv_wt<<<dim3(24, 12), blk, 0, stream>>>(Wkv, WkvT, 2 * DIMSZ);
    conv_wt<<<dim3(12, 12), blk, 0, stream>>>(Wout, WoutT, DIMSZ);
    conv_bf16<<<dim3(6144), blk, 0, stream>>>(x_kv, xkv_bf);
    // kv-projection -> TRANSPOSED kvpT = [elu(x_kv@Wk)+1 | x_kv@Wv]^T
    gemm_bt<3, 768><<<dim3(6, 256), blk, 0, stream>>>(xkv_bf, WkvT, kvpT, nullptr);
    // kv state + ksum via MFMA (partials), then reduce
    kv_state_mfma<<<dim3(768), blk, 0, stream>>>(kvpT, pkv, pks);
    kv_reduce<<<dim3(48), blk, 0, stream>>>(pkv, pks, kv, ksum);
    // q-projection (xq_bf/q_bf overwrite dead kvpT region)
    conv_bf16<<<dim3(6144), blk, 0, stream>>>(x_q, xq_bf);
    gemm_bt<0, 384><<<dim3(3, 256), blk, 0, stream>>>(xq_bf, WqT, q_bf, nullptr);
    // attn = (q @ kv) * z   (z fused; in-place over q)
    attn_mfma<<<dim3(768), blk, 0, stream>>>(q_bf, kv, ksum, q_bf);
    // out = attn @ Wout + bout
    gemm_bt<2, 384><<<dim3(3, 256), blk, 0, stream>>>(q_bf, WoutT, out, bout);
}